// Round 8
// baseline (4027.334 us; speedup 1.0000x reference)
//
#include <hip/hip_runtime.h>
#include <cstdint>
#include <cstddef>

// ---------------------------------------------------------------------------
// PointNet++ (B=8, N=4096, K=64, N1=2048, N2=512, r1=0.2, r2=0.4), fp32.
// Selection stages (FPS argmax, ball-query top-k) use __f*_rn intrinsics in
// numpy's association order -> selected index sets match the reference
// bit-exactly; MLP math uses fma freely.
// R8: non-FPS pipeline reverted to R6 (R7 fusion regressed — register-spill
// confound). FPS step loop restructured to attack the ~615ns serial floor:
//   - 256 threads (4 waves, 1 wave/SIMD): halves barrier participants.
//   - coords ride in REGISTERS through the reduce: key-only DPP, readlane(63)
//     broadcast, unique winning lane plain-writes {key, xyz} to double-
//     buffered partials. No LDS atomic, no post-barrier coord hop.
// (R5 carry-over: Morton-bucket sort + exact bbox pruning, bit-exact since
//  min() has no rounding; key=(d2bits<<24)|((~orig&0xFFF)<<12)|spos.)
// ---------------------------------------------------------------------------

static constexpr int Bc = 8;     // batch (clouds)
static constexpr int Np = 4096;  // points per cloud
static constexpr int Kn = 64;    // max neighbors
static constexpr int M1 = 2048;  // SA1 centers
static constexpr int M2 = 512;   // SA2 centers
static constexpr int LDX = 132;  // row stride of X = [x2 (128) | c2 (3) | pad]

#define DEVINL __device__ __forceinline__

// exact replication of np: ((dx*dx + dy*dy) + dz*dz), no fma contraction
DEVINL float d2_exact(float ax, float ay, float az, float bx, float by, float bz) {
    float dx = __fsub_rn(ax, bx);
    float dy = __fsub_rn(ay, by);
    float dz = __fsub_rn(az, bz);
    float xx = __fmul_rn(dx, dx);
    float yy = __fmul_rn(dy, dy);
    float zz = __fmul_rn(dz, dz);
    return __fadd_rn(__fadd_rn(xx, yy), zz);
}

template <int CTRL, int RM, int BM>
DEVINL unsigned long long dpp_max_step(unsigned long long k) {
    unsigned lo = (unsigned)k, hi = (unsigned)(k >> 32);
    unsigned slo = (unsigned)__builtin_amdgcn_update_dpp(0, (int)lo, CTRL, RM, BM, true);
    unsigned shi = (unsigned)__builtin_amdgcn_update_dpp(0, (int)hi, CTRL, RM, BM, true);
    unsigned long long s = ((unsigned long long)shi << 32) | (unsigned long long)slo;
    return s > k ? s : k;
}

DEVINL unsigned long long wave_max_u64_dpp(unsigned long long k) {
    k = dpp_max_step<0x111, 0xf, 0xf>(k);  // row_shr:1
    k = dpp_max_step<0x112, 0xf, 0xf>(k);  // row_shr:2
    k = dpp_max_step<0x114, 0xf, 0xf>(k);  // row_shr:4
    k = dpp_max_step<0x118, 0xf, 0xf>(k);  // row_shr:8
    k = dpp_max_step<0x142, 0xa, 0xf>(k);  // row_bcast:15
    k = dpp_max_step<0x143, 0xc, 0xf>(k);  // row_bcast:31 -> lane 63 = wave max
    return k;
}

// cell grid 4x8x8 = 256 cells (fits a 256-thread scan)
DEVINL unsigned cell_of(float x, float y, float z) {
    int ix = (int)(x * 4.0f); ix = ix < 0 ? 0 : (ix > 3 ? 3 : ix);
    int iy = (int)(y * 8.0f); iy = iy < 0 ? 0 : (iy > 7 ? 7 : iy);
    int iz = (int)(z * 8.0f); iz = iz < 0 ? 0 : (iz > 7 ? 7 : iz);
    return ((unsigned)ix << 6) | ((unsigned)iy << 3) | (unsigned)iz;
}

// inclusive Hillis-Steele scan over 256 entries (thread t owns entry t).
DEVINL unsigned* scan256(unsigned* h0, unsigned* h1, int t) {
    unsigned* src = h0; unsigned* dst = h1;
    for (int d = 1; d < 256; d <<= 1) {
        unsigned v = src[t];
        if (t >= d) v += src[t - d];
        dst[t] = v;
        __syncthreads();
        unsigned* tmp = src; src = dst; dst = tmp;
    }
    return src;
}

// select between two (key, coords) partials
DEVINL void sel2(unsigned long long ka, float4 ca, unsigned long long kb, float4 cb,
                 unsigned long long& ko, float4& co) {
    bool tk = kb > ka;
    ko = tk ? kb : ka;
    co.x = tk ? cb.x : ca.x;
    co.y = tk ? cb.y : ca.y;
    co.z = tk ? cb.z : ca.z;
}

DEVINL unsigned long long readlane63_u64(unsigned long long v) {
    unsigned lo = (unsigned)__builtin_amdgcn_readlane((int)(unsigned)v, 63);
    unsigned hi = (unsigned)__builtin_amdgcn_readlane((int)(unsigned)(v >> 32), 63);
    return ((unsigned long long)hi << 32) | (unsigned long long)lo;
}

// ---------------------------------------------------------------------------
// Merged FPS with exact pruning: one block (256 thr, 4 waves) per cloud.
// Double-buffered {key, coords} partials; winning lane identified by
// readlane(63) broadcast + unique-key compare. No atomics, no coord hop.
// ---------------------------------------------------------------------------
__global__ __launch_bounds__(256)
void fps2x_kernel(const float* __restrict__ pos, float* __restrict__ c1,
                  float* __restrict__ c2, float* __restrict__ X) {
    constexpr int NT = 256;
    __shared__ float scx[Np], scy[Np], scz[Np];        // sorted coords (48 KB)
    __shared__ unsigned spk[Np];                       // ((~orig&0xFFF)<<12)|spos (16 KB)
    __shared__ alignas(16) float s2c[M1 * 3];          // phase-1 selections (24 KB)
    __shared__ alignas(16) float s3c[M2 * 3];          // phase-2 selections (6 KB)
    __shared__ unsigned h0[256], h1[256];
    __shared__ alignas(16) unsigned long long pK[2][4];
    __shared__ alignas(16) float4 pC[2][4];
    const int b = blockIdx.x;
    const int t = threadIdx.x;
    const int wid = t >> 6;

    // ===================== phase 1: pos -> s2c =====================
    {
        constexpr int PT = Np / NT;  // 16
        const float* base = pos + (size_t)b * Np * 3;
        float gx[PT], gy[PT], gz[PT];
        unsigned gc[PT];
        #pragma unroll
        for (int j = 0; j < PT; ++j) {
            int p = j * NT + t;
            gx[j] = base[p * 3 + 0];
            gy[j] = base[p * 3 + 1];
            gz[j] = base[p * 3 + 2];
            gc[j] = cell_of(gx[j], gy[j], gz[j]);
        }
        float x0 = base[0], y0 = base[1], z0 = base[2];
        h0[t] = 0;
        __syncthreads();
        #pragma unroll
        for (int j = 0; j < PT; ++j) atomicAdd(&h0[gc[j]], 1u);
        __syncthreads();
        unsigned cnt = h0[t];
        unsigned* inc = scan256(h0, h1, t);
        inc[t] -= cnt;                 // exclusive offset -> running cursor
        __syncthreads();
        #pragma unroll
        for (int j = 0; j < PT; ++j) {
            unsigned p = atomicAdd(&inc[gc[j]], 1u);
            scx[p] = gx[j]; scy[p] = gy[j]; scz[p] = gz[j];
            spk[p] = ((0xFFFu - (unsigned)(j * NT + t)) << 12) | p;
        }
        __syncthreads();

        float px[PT], py[PT], pz[PT], mind[PT];
        unsigned oi[PT];
        #pragma unroll
        for (int j = 0; j < PT; ++j) {
            int p = t * PT + j;
            px[j] = scx[p]; py[j] = scy[p]; pz[j] = scz[p];
            oi[j] = spk[p];
        }
        float lox = px[0], hix = px[0], loy = py[0], hiy = py[0], loz = pz[0], hiz = pz[0];
        #pragma unroll
        for (int j = 1; j < PT; ++j) {
            lox = fminf(lox, px[j]); hix = fmaxf(hix, px[j]);
            loy = fminf(loy, py[j]); hiy = fmaxf(hiy, py[j]);
            loz = fminf(loz, pz[j]); hiz = fmaxf(hiz, pz[j]);
        }

        unsigned long long ck = 0;
        float bx = 0.f, by = 0.f, bz = 0.f;
        #pragma unroll
        for (int j = 0; j < PT; ++j) {
            float d = d2_exact(px[j], py[j], pz[j], x0, y0, z0);
            mind[j] = d;
            unsigned long long kj =
                ((unsigned long long)__float_as_uint(d) << 24) | (unsigned long long)oi[j];
            if (kj > ck) { ck = kj; bx = px[j]; by = py[j]; bz = pz[j]; }
        }
        float bmax = __uint_as_float((unsigned)(ck >> 24));
        unsigned long long wred = wave_max_u64_dpp(ck);
        unsigned long long wk = readlane63_u64(wred);
        if (ck == wk) { pK[1][wid] = ck; pC[1][wid] = make_float4(bx, by, bz, 0.f); }
        if (t == 0) { s2c[0] = x0; s2c[1] = y0; s2c[2] = z0; }
        for (int s = 1; s < M1; ++s) {
            __syncthreads();           // one barrier per step
            const int rb = s & 1;
            const ulonglong2* pk2 = (const ulonglong2*)pK[rb];
            ulonglong2 k01 = pk2[0], k23 = pk2[1];
            float4 q0 = pC[rb][0], q1 = pC[rb][1], q2 = pC[rb][2], q3 = pC[rb][3];
            unsigned long long m01, m23, mw;
            float4 s01, s23, sw;
            sel2(k01.x, q0, k01.y, q1, m01, s01);
            sel2(k23.x, q2, k23.y, q3, m23, s23);
            sel2(m01, s01, m23, s23, mw, sw);
            float cx = sw.x, cy = sw.y, cz = sw.z;
            if (t == 0) {
                s2c[s * 3 + 0] = cx; s2c[s * 3 + 1] = cy; s2c[s * 3 + 2] = cz;
            }
            float dxv = fmaxf(fmaxf(lox - cx, cx - hix), 0.0f);
            float dyv = fmaxf(fmaxf(loy - cy, cy - hiy), 0.0f);
            float dzv = fmaxf(fmaxf(loz - cz, cz - hiz), 0.0f);
            float L = dxv * dxv + dyv * dyv + dzv * dzv;
            bool fire = (L * 0.999f <= bmax);
            if (fire) {
                unsigned long long nck = 0;
                float nbx = 0.f, nby = 0.f, nbz = 0.f;
                #pragma unroll
                for (int j = 0; j < PT; ++j) {
                    float d = d2_exact(px[j], py[j], pz[j], cx, cy, cz);
                    float m = fminf(mind[j], d);
                    mind[j] = m;
                    unsigned long long kj =
                        ((unsigned long long)__float_as_uint(m) << 24) | (unsigned long long)oi[j];
                    if (kj > nck) { nck = kj; nbx = px[j]; nby = py[j]; nbz = pz[j]; }
                }
                ck = nck; bx = nbx; by = nby; bz = nbz;
                bmax = __uint_as_float((unsigned)(ck >> 24));
            }
            if (__ballot(fire) != 0ull) {
                wred = wave_max_u64_dpp(ck);
                wk = readlane63_u64(wred);
            }
            const int nb = (s + 1) & 1;
            if (ck == wk) { pK[nb][wid] = ck; pC[nb][wid] = make_float4(bx, by, bz, 0.f); }
        }
    }
    __syncthreads();   // phase-1 done; s2c complete

    // bulk write c1 from s2c (coalesced float4)
    {
        const float4* s2c4 = (const float4*)s2c;
        float4* c1b = (float4*)(c1 + (size_t)b * M1 * 3);
        for (int i = t; i < M1 * 3 / 4; i += NT) c1b[i] = s2c4[i];
    }
    __syncthreads();

    // ===================== phase 2: s2c -> s3c =====================
    {
        constexpr int PT = M1 / NT;  // 8
        float gx[PT], gy[PT], gz[PT];
        unsigned gc[PT];
        #pragma unroll
        for (int j = 0; j < PT; ++j) {
            int p = j * NT + t;
            gx[j] = s2c[p * 3 + 0];
            gy[j] = s2c[p * 3 + 1];
            gz[j] = s2c[p * 3 + 2];
            gc[j] = cell_of(gx[j], gy[j], gz[j]);
        }
        float x0 = s2c[0], y0 = s2c[1], z0 = s2c[2];
        h0[t] = 0;
        __syncthreads();
        #pragma unroll
        for (int j = 0; j < PT; ++j) atomicAdd(&h0[gc[j]], 1u);
        __syncthreads();
        unsigned cnt = h0[t];
        unsigned* inc = scan256(h0, h1, t);
        inc[t] -= cnt;
        __syncthreads();
        #pragma unroll
        for (int j = 0; j < PT; ++j) {
            unsigned p = atomicAdd(&inc[gc[j]], 1u);
            scx[p] = gx[j]; scy[p] = gy[j]; scz[p] = gz[j];
            spk[p] = ((0xFFFu - (unsigned)(j * NT + t)) << 12) | p;
        }
        __syncthreads();

        float px[PT], py[PT], pz[PT], mind[PT];
        unsigned oi[PT];
        #pragma unroll
        for (int j = 0; j < PT; ++j) {
            int p = t * PT + j;
            px[j] = scx[p]; py[j] = scy[p]; pz[j] = scz[p];
            oi[j] = spk[p];
        }
        float lox = px[0], hix = px[0], loy = py[0], hiy = py[0], loz = pz[0], hiz = pz[0];
        #pragma unroll
        for (int j = 1; j < PT; ++j) {
            lox = fminf(lox, px[j]); hix = fmaxf(hix, px[j]);
            loy = fminf(loy, py[j]); hiy = fmaxf(hiy, py[j]);
            loz = fminf(loz, pz[j]); hiz = fmaxf(hiz, pz[j]);
        }

        unsigned long long ck = 0;
        float bx = 0.f, by = 0.f, bz = 0.f;
        #pragma unroll
        for (int j = 0; j < PT; ++j) {
            float d = d2_exact(px[j], py[j], pz[j], x0, y0, z0);
            mind[j] = d;
            unsigned long long kj =
                ((unsigned long long)__float_as_uint(d) << 24) | (unsigned long long)oi[j];
            if (kj > ck) { ck = kj; bx = px[j]; by = py[j]; bz = pz[j]; }
        }
        float bmax = __uint_as_float((unsigned)(ck >> 24));
        unsigned long long wred = wave_max_u64_dpp(ck);
        unsigned long long wk = readlane63_u64(wred);
        if (ck == wk) { pK[1][wid] = ck; pC[1][wid] = make_float4(bx, by, bz, 0.f); }
        if (t == 0) { s3c[0] = x0; s3c[1] = y0; s3c[2] = z0; }
        for (int s = 1; s < M2; ++s) {
            __syncthreads();
            const int rb = s & 1;
            const ulonglong2* pk2 = (const ulonglong2*)pK[rb];
            ulonglong2 k01 = pk2[0], k23 = pk2[1];
            float4 q0 = pC[rb][0], q1 = pC[rb][1], q2 = pC[rb][2], q3 = pC[rb][3];
            unsigned long long m01, m23, mw;
            float4 s01, s23, sw;
            sel2(k01.x, q0, k01.y, q1, m01, s01);
            sel2(k23.x, q2, k23.y, q3, m23, s23);
            sel2(m01, s01, m23, s23, mw, sw);
            float cx = sw.x, cy = sw.y, cz = sw.z;
            if (t == 0) {
                s3c[s * 3 + 0] = cx; s3c[s * 3 + 1] = cy; s3c[s * 3 + 2] = cz;
            }
            float dxv = fmaxf(fmaxf(lox - cx, cx - hix), 0.0f);
            float dyv = fmaxf(fmaxf(loy - cy, cy - hiy), 0.0f);
            float dzv = fmaxf(fmaxf(loz - cz, cz - hiz), 0.0f);
            float L = dxv * dxv + dyv * dyv + dzv * dzv;
            bool fire = (L * 0.999f <= bmax);
            if (fire) {
                unsigned long long nck = 0;
                float nbx = 0.f, nby = 0.f, nbz = 0.f;
                #pragma unroll
                for (int j = 0; j < PT; ++j) {
                    float d = d2_exact(px[j], py[j], pz[j], cx, cy, cz);
                    float m = fminf(mind[j], d);
                    mind[j] = m;
                    unsigned long long kj =
                        ((unsigned long long)__float_as_uint(m) << 24) | (unsigned long long)oi[j];
                    if (kj > nck) { nck = kj; nbx = px[j]; nby = py[j]; nbz = pz[j]; }
                }
                ck = nck; bx = nbx; by = nby; bz = nbz;
                bmax = __uint_as_float((unsigned)(ck >> 24));
            }
            if (__ballot(fire) != 0ull) {
                wred = wave_max_u64_dpp(ck);
                wk = readlane63_u64(wred);
            }
            const int nb = (s + 1) & 1;
            if (ck == wk) { pK[nb][wid] = ck; pC[nb][wid] = make_float4(bx, by, bz, 0.f); }
        }
    }
    __syncthreads();   // s3c complete

    // bulk write c2 + X[:,128..130] from s3c
    {
        const float4* s3c4 = (const float4*)s3c;
        float4* c2b = (float4*)(c2 + (size_t)b * M2 * 3);
        for (int i = t; i < M2 * 3 / 4; i += NT) c2b[i] = s3c4[i];
        for (int s = t; s < M2; s += NT) {
            float* xr = X + (size_t)(b * M2 + s) * LDX;
            xr[128] = s3c[s * 3 + 0];
            xr[129] = s3c[s * 3 + 1];
            xr[130] = s3c[s * 3 + 2];
        }
    }
}

// ---------------------------------------------------------------------------
// Ball query: one wave per center (R6 version, unchanged).
// ---------------------------------------------------------------------------
template <int NPT>
__global__ __launch_bounds__(256)
void bq_kernel(const float* __restrict__ pts, const float* __restrict__ ctr,
               int mshift, float r2, int* __restrict__ nbr) {
    constexpr int CH = NPT / 64;
    constexpr int CAP = 1024;            // per-wave candidate cap (fallback if exceeded)
    __shared__ uint2 cbuf[4][CAP];
    const int lane = threadIdx.x & 63;
    const int wl = threadIdx.x >> 6;
    int w = __builtin_amdgcn_readfirstlane((int)(blockIdx.x * 4 + wl));
    const int b = w >> mshift;
    const float* pb = pts + (size_t)b * NPT * 3;
    const float* cp = ctr + (size_t)w * 3;
    float cx = cp[0], cy = cp[1], cz = cp[2];
    const unsigned r2b = __float_as_uint(r2);

    unsigned ub[CH];
    int cnt = 0;
    #pragma unroll
    for (int j = 0; j < CH; ++j) {
        int p = j * 64 + lane;
        float d = d2_exact(pb[p * 3 + 0], pb[p * 3 + 1], pb[p * 3 + 2], cx, cy, cz);
        ub[j] = __float_as_uint(d);   // d >= 0 -> bits monotonic
        cnt += __popcll(__ballot(ub[j] <= r2b));
    }
    int* out = nbr + (size_t)w * Kn;
    const unsigned long long lml = (1ull << lane) - 1ull;

    if (cnt <= Kn) {
        int basep = 0;
        #pragma unroll
        for (int j = 0; j < CH; ++j) {
            bool v = ub[j] <= r2b;
            unsigned long long mk = __ballot(v);
            if (v) out[basep + __popcll(mk & lml)] = j * 64 + lane;
            basep += __popcll(mk);
        }
        if (lane >= cnt) out[lane] = -1;
    } else if (cnt <= CAP) {
        uint2* buf = cbuf[wl];
        int basep = 0;
        #pragma unroll
        for (int j = 0; j < CH; ++j) {
            bool v = ub[j] <= r2b;
            unsigned long long mk = __ballot(v);
            if (v) buf[basep + __popcll(mk & lml)] =
                       make_uint2(ub[j], (unsigned)(j * 64 + lane));
            basep += __popcll(mk);
        }
        const int C2 = (cnt + 63) >> 6;   // wave-uniform
        unsigned cb[CAP / 64], ci[CAP / 64];
        #pragma unroll
        for (int e = 0; e < CAP / 64; ++e) {
            if (e >= C2) break;
            int p = e * 64 + lane;
            uint2 v = buf[p];
            cb[e] = (p < cnt) ? v.x : 0xFFFFFFFFu;
            ci[e] = v.y;
        }
        unsigned lo = 0, hi = r2b;
        while (lo < hi) {
            unsigned mid = lo + ((hi - lo) >> 1);
            int c = 0;
            #pragma unroll
            for (int e = 0; e < CAP / 64; ++e) {
                if (e >= C2) break;
                c += __popcll(__ballot(cb[e] <= mid));
            }
            if (c >= Kn) hi = mid; else lo = mid + 1;
        }
        const unsigned tt = lo;
        int cntLess = 0;
        #pragma unroll
        for (int e = 0; e < CAP / 64; ++e) {
            if (e >= C2) break;
            cntLess += __popcll(__ballot(cb[e] < tt));
        }
        const int quota = Kn - cntLess;
        int baseLt = 0, eqseen = 0;
        #pragma unroll
        for (int e = 0; e < CAP / 64; ++e) {
            if (e >= C2) break;
            bool lt = cb[e] < tt;
            bool eq = cb[e] == tt;
            unsigned long long mlt = __ballot(lt);
            unsigned long long meq = __ballot(eq);
            if (lt) out[baseLt + __popcll(mlt & lml)] = (int)ci[e];
            if (eq) {
                int rr = eqseen + __popcll(meq & lml);
                if (rr < quota) out[cntLess + rr] = (int)ci[e];
            }
            baseLt += __popcll(mlt);
            eqseen += __popcll(meq);
        }
    } else {
        unsigned lo = 0, hi = r2b;
        while (lo < hi) {
            unsigned mid = lo + ((hi - lo) >> 1);
            int c = 0;
            #pragma unroll
            for (int j = 0; j < CH; ++j) c += __popcll(__ballot(ub[j] <= mid));
            if (c >= Kn) hi = mid; else lo = mid + 1;
        }
        const unsigned tt = lo;
        int cntLess = 0;
        #pragma unroll
        for (int j = 0; j < CH; ++j) cntLess += __popcll(__ballot(ub[j] < tt));
        const int quota = Kn - cntLess;
        int baseLt = 0, eqseen = 0;
        #pragma unroll
        for (int j = 0; j < CH; ++j) {
            bool lt = ub[j] < tt;
            bool eq = ub[j] == tt;
            unsigned long long mlt = __ballot(lt);
            unsigned long long meq = __ballot(eq);
            if (lt) out[baseLt + __popcll(mlt & lml)] = j * 64 + lane;
            if (eq) {
                int rr = eqseen + __popcll(meq & lml);
                if (rr < quota) out[cntLess + rr] = j * 64 + lane;
            }
            baseLt += __popcll(mlt);
            eqseen += __popcll(meq);
        }
    }
}

// ---------------------------------------------------------------------------
// MLP1 (SA1): wave per center, lane per neighbor (R6 version, unchanged).
// ---------------------------------------------------------------------------
__global__ __launch_bounds__(256)
void mlp1_kernel(const float* __restrict__ pos, const float* __restrict__ c1,
                 const int* __restrict__ nbr, const float* __restrict__ w1aT,
                 const float* __restrict__ w1bT, const float* __restrict__ b1b,
                 float* __restrict__ x1) {
    const int lane = threadIdx.x & 63;
    int w = __builtin_amdgcn_readfirstlane((int)(blockIdx.x * 4 + (threadIdx.x >> 6)));
    const int b = w >> 11;
    const int ii = nbr[(size_t)w * Kn + lane];
    const bool valid = ii >= 0;
    const int i2 = valid ? ii : 0;
    const float* pp = pos + ((size_t)b * Np + i2) * 3;
    const float* cc = c1 + (size_t)w * 3;
    float rx = pp[0] - cc[0], ry = pp[1] - cc[1], rz = pp[2] - cc[2];
    float h1[64];
    #pragma unroll
    for (int h = 0; h < 64; ++h) {
        float4 wv = ((const float4*)w1aT)[h];
        float a = fmaf(rx, wv.x, fmaf(ry, wv.y, fmaf(rz, wv.z, wv.w)));
        h1[h] = fmaxf(a, 0.0f);
    }
    float* orow = x1 + (size_t)w * 64;
    for (int c4 = 0; c4 < 16; ++c4) {
        float v4[4];
        #pragma unroll
        for (int cq = 0; cq < 4; ++cq) {
            int c = c4 * 4 + cq;
            float acc = b1b[c];
            const float4* wr = (const float4*)(w1bT + (size_t)c * 64);
            #pragma unroll
            for (int q = 0; q < 16; ++q) {
                float4 wv = wr[q];
                acc = fmaf(h1[4 * q + 0], wv.x, acc);
                acc = fmaf(h1[4 * q + 1], wv.y, acc);
                acc = fmaf(h1[4 * q + 2], wv.z, acc);
                acc = fmaf(h1[4 * q + 3], wv.w, acc);
            }
            float v = fmaxf(acc, 0.0f);
            v = valid ? v : -__builtin_inff();
            #pragma unroll
            for (int o = 32; o > 0; o >>= 1) v = fmaxf(v, __shfl_xor(v, o, 64));
            v4[cq] = v;
        }
        if (lane == 0)
            ((float4*)orow)[c4] = make_float4(v4[0], v4[1], v4[2], v4[3]);
    }
}

// ---------------------------------------------------------------------------
// MLP2 (SA2): wave per center, lane per neighbor (R6 version, unchanged).
// ---------------------------------------------------------------------------
__global__ __launch_bounds__(256)
void mlp2_kernel(const float* __restrict__ x1, const float* __restrict__ c1,
                 const float* __restrict__ c2, const int* __restrict__ nbr2,
                 const float* __restrict__ w2aT, const float* __restrict__ w2bT,
                 const float* __restrict__ b2b, float* __restrict__ X) {
    const int lane = threadIdx.x & 63;
    int w = __builtin_amdgcn_readfirstlane((int)(blockIdx.x * 4 + (threadIdx.x >> 6)));
    const int b = w >> 9;
    const int ii = nbr2[(size_t)w * Kn + lane];
    const bool valid = ii >= 0;
    const int i2 = valid ? ii : 0;

    float x[68];
    const float4* xr = (const float4*)(x1 + ((size_t)b * M1 + i2) * 64);
    #pragma unroll
    for (int q = 0; q < 16; ++q) {
        float4 v = xr[q];
        x[4 * q + 0] = v.x; x[4 * q + 1] = v.y;
        x[4 * q + 2] = v.z; x[4 * q + 3] = v.w;
    }
    const float* cc = c2 + (size_t)w * 3;
    const float* cp = c1 + ((size_t)b * M1 + i2) * 3;
    x[64] = cp[0] - cc[0];
    x[65] = cp[1] - cc[1];
    x[66] = cp[2] - cc[2];
    x[67] = 0.0f;

    float h1[128];
    #pragma unroll
    for (int h = 0; h < 128; ++h) {
        const float4* r4 = (const float4*)(w2aT + (size_t)h * 80);
        float acc = 0.0f;
        #pragma unroll
        for (int q = 0; q < 16; ++q) {
            float4 wv = r4[q];
            acc = fmaf(x[4 * q + 0], wv.x, acc);
            acc = fmaf(x[4 * q + 1], wv.y, acc);
            acc = fmaf(x[4 * q + 2], wv.z, acc);
            acc = fmaf(x[4 * q + 3], wv.w, acc);
        }
        float4 tl = r4[16];   // w64, w65, w66, bias
        acc = fmaf(x[64], tl.x, acc);
        acc = fmaf(x[65], tl.y, acc);
        acc = fmaf(x[66], tl.z, acc);
        acc += tl.w;
        h1[h] = fmaxf(acc, 0.0f);
    }
    float* orow = X + (size_t)w * LDX;
    for (int c4 = 0; c4 < 32; ++c4) {
        float v4[4];
        #pragma unroll
        for (int cq = 0; cq < 4; ++cq) {
            int c = c4 * 4 + cq;
            float acc = b2b[c];
            const float4* wr = (const float4*)(w2bT + (size_t)c * 128);
            #pragma unroll
            for (int q = 0; q < 32; ++q) {
                float4 wv = wr[q];
                acc = fmaf(h1[4 * q + 0], wv.x, acc);
                acc = fmaf(h1[4 * q + 1], wv.y, acc);
                acc = fmaf(h1[4 * q + 2], wv.z, acc);
                acc = fmaf(h1[4 * q + 3], wv.w, acc);
            }
            float v = fmaxf(acc, 0.0f);
            v = valid ? v : -__builtin_inff();
            #pragma unroll
            for (int o = 32; o > 0; o >>= 1) v = fmaxf(v, __shfl_xor(v, o, 64));
            v4[cq] = v;
        }
        if (lane == 0) {
            orow[c4 * 4 + 0] = v4[0]; orow[c4 * 4 + 1] = v4[1];
            orow[c4 * 4 + 2] = v4[2]; orow[c4 * 4 + 3] = v4[3];
        }
    }
}

// ---------------------------------------------------------------------------
// GEMM1 (R6 version, unchanged).
// ---------------------------------------------------------------------------
__global__ __launch_bounds__(256)
void gemm1_kernel(const float* __restrict__ X, const float* __restrict__ w3a,
                  const float* __restrict__ b3a, float* __restrict__ H) {
    const int r = blockIdx.x;
    const int c = threadIdx.x;
    const float* xr = X + (size_t)r * LDX;
    float acc = b3a[c];
    for (int i = 0; i < 131; ++i)
        acc = fmaf(xr[i], w3a[(size_t)i * 256 + c], acc);
    H[(size_t)r * 256 + c] = fmaxf(acc, 0.0f);
}

// ---------------------------------------------------------------------------
// GEMM2 fused with per-tile row max (R6 version, unchanged).
// ---------------------------------------------------------------------------
__global__ __launch_bounds__(256)
void gemm2_kernel(const float* __restrict__ H, const float* __restrict__ w3b,
                  float* __restrict__ part) {
    __shared__ float As[32][33];
    __shared__ float Bs[32][64];
    __shared__ float red[8][64];
    const int bidx = blockIdx.x;
    const int nt = bidx & 15;
    const int mt = (bidx >> 4) & 15;
    const int b = bidx >> 8;
    const int row0 = b * M2 + mt * 32;
    const int col0 = nt * 64;
    const int t = threadIdx.x;
    const int rg = t >> 5, cg = t & 31;

    float acc[4][2] = {{0.f, 0.f}, {0.f, 0.f}, {0.f, 0.f}, {0.f, 0.f}};
    for (int k0 = 0; k0 < 256; k0 += 32) {
        #pragma unroll
        for (int q = 0; q < 4; ++q) {
            int id = t + q * 256;
            As[id >> 5][id & 31] = H[(size_t)(row0 + (id >> 5)) * 256 + k0 + (id & 31)];
        }
        #pragma unroll
        for (int q = 0; q < 8; ++q) {
            int id = t + q * 256;
            Bs[id >> 6][id & 63] = w3b[(size_t)(k0 + (id >> 6)) * 1024 + col0 + (id & 63)];
        }
        __syncthreads();
        #pragma unroll
        for (int kk = 0; kk < 32; ++kk) {
            float b0 = Bs[kk][cg * 2 + 0];
            float b1 = Bs[kk][cg * 2 + 1];
            #pragma unroll
            for (int j = 0; j < 4; ++j) {
                float a = As[rg * 4 + j][kk];
                acc[j][0] = fmaf(a, b0, acc[j][0]);
                acc[j][1] = fmaf(a, b1, acc[j][1]);
            }
        }
        __syncthreads();
    }
    float m0 = fmaxf(fmaxf(acc[0][0], acc[1][0]), fmaxf(acc[2][0], acc[3][0]));
    float m1 = fmaxf(fmaxf(acc[0][1], acc[1][1]), fmaxf(acc[2][1], acc[3][1]));
    red[rg][cg * 2 + 0] = m0;
    red[rg][cg * 2 + 1] = m1;
    __syncthreads();
    if (t < 64) {
        float v = red[0][t];
        #pragma unroll
        for (int q = 1; q < 8; ++q) v = fmaxf(v, red[q][t]);
        part[((size_t)b * 16 + mt) * 1024 + col0 + t] = v;
    }
}

// ---------------------------------------------------------------------------
// Final max over the 16 m-tiles per cloud + bias (R6 version, unchanged).
// ---------------------------------------------------------------------------
__global__ __launch_bounds__(256)
void rmax_kernel(const float* __restrict__ part, const float* __restrict__ b3b,
                 float* __restrict__ out) {
    int i = blockIdx.x * 256 + threadIdx.x;  // 8192 = B*1024
    int b = i >> 10, c = i & 1023;
    float v = -__builtin_inff();
    #pragma unroll
    for (int tt = 0; tt < 16; ++tt)
        v = fmaxf(v, part[((size_t)b * 16 + tt) * 1024 + c]);
    out[i] = v + b3b[c];
}

// ---------------------------------------------------------------------------
// Weight transposes (R6 version, unchanged).
// ---------------------------------------------------------------------------
__global__ __launch_bounds__(256)
void prep_kernel(const float* __restrict__ w1a, const float* __restrict__ b1a,
                 const float* __restrict__ w1b, const float* __restrict__ w2a,
                 const float* __restrict__ b2a, const float* __restrict__ w2b,
                 float* __restrict__ w1aT, float* __restrict__ w1bT,
                 float* __restrict__ w2aT, float* __restrict__ w2bT) {
    int i = blockIdx.x * 256 + threadIdx.x;  // 0..16383
    if (i < 64 * 4) {
        int h = i >> 2, d = i & 3;
        w1aT[i] = (d < 3) ? w1a[d * 64 + h] : b1a[h];
    }
    if (i < 64 * 64) {
        int c = i >> 6, h = i & 63;
        w1bT[i] = w1b[h * 64 + c];
    }
    if (i < 128 * 80) {
        int h = i / 80, d = i - h * 80;
        w2aT[i] = (d < 67) ? w2a[d * 128 + h] : ((d == 67) ? b2a[h] : 0.0f);
    }
    {
        int c = i >> 7, h = i & 127;
        w2bT[i] = w2b[h * 128 + c];
    }
}

// ---------------------------------------------------------------------------
extern "C" void kernel_launch(void* const* d_in, const int* in_sizes, int n_in,
                              void* d_out, int out_size, void* d_ws, size_t ws_size,
                              hipStream_t stream) {
    const float* pos = (const float*)d_in[0];
    const float* w1a = (const float*)d_in[1];
    const float* b1a = (const float*)d_in[2];
    const float* w1b = (const float*)d_in[3];
    const float* b1b = (const float*)d_in[4];
    const float* w2a = (const float*)d_in[5];
    const float* b2a = (const float*)d_in[6];
    const float* w2b = (const float*)d_in[7];
    const float* b2b = (const float*)d_in[8];
    const float* w3a = (const float*)d_in[9];
    const float* b3a = (const float*)d_in[10];
    const float* w3b = (const float*)d_in[11];
    const float* b3b = (const float*)d_in[12];
    float* out = (float*)d_out;

    char* ws = (char*)d_ws;
    size_t off = 0;
    auto alloc = [&](size_t bytes) -> char* {
        char* p = ws + off;
        off += (bytes + 255) & ~(size_t)255;
        return p;
    };
    float* c1   = (float*)alloc(sizeof(float) * Bc * M1 * 3);
    float* c2   = (float*)alloc(sizeof(float) * Bc * M2 * 3);
    int*   nbr1 = (int*)alloc(sizeof(int) * Bc * M1 * Kn);
    int*   nbr2 = (int*)alloc(sizeof(int) * Bc * M2 * Kn);
    float* x1   = (float*)alloc(sizeof(float) * Bc * M1 * 64);
    float* X    = (float*)alloc(sizeof(float) * Bc * M2 * LDX);
    float* H    = (float*)alloc(sizeof(float) * Bc * M2 * 256);
    float* part = (float*)alloc(sizeof(float) * Bc * 16 * 1024);
    float* w1aT = (float*)alloc(sizeof(float) * 64 * 4);
    float* w1bT = (float*)alloc(sizeof(float) * 64 * 64);
    float* w2aT = (float*)alloc(sizeof(float) * 128 * 80);
    float* w2bT = (float*)alloc(sizeof(float) * 128 * 128);

    prep_kernel<<<dim3(64), dim3(256), 0, stream>>>(w1a, b1a, w1b, w2a, b2a, w2b,
                                                    w1aT, w1bT, w2aT, w2bT);
    fps2x_kernel<<<dim3(Bc), dim3(256), 0, stream>>>(pos, c1, c2, X);
    bq_kernel<Np><<<dim3(Bc * M1 / 4), dim3(256), 0, stream>>>(
        pos, c1, 11, (float)(0.2 * 0.2), nbr1);
    mlp1_kernel<<<dim3(Bc * M1 / 4), dim3(256), 0, stream>>>(
        pos, c1, nbr1, w1aT, w1bT, b1b, x1);
    bq_kernel<M1><<<dim3(Bc * M2 / 4), dim3(256), 0, stream>>>(
        c1, c2, 9, (float)(0.4 * 0.4), nbr2);
    mlp2_kernel<<<dim3(Bc * M2 / 4), dim3(256), 0, stream>>>(
        x1, c1, c2, nbr2, w2aT, w2bT, b2b, X);
    gemm1_kernel<<<dim3(Bc * M2), dim3(256), 0, stream>>>(X, w3a, b3a, H);
    gemm2_kernel<<<dim3(Bc * 16 * 16), dim3(256), 0, stream>>>(H, w3b, part);
    rmax_kernel<<<dim3(32), dim3(256), 0, stream>>>(part, b3b, out);
}

// Round 9
// 2499.565 us; speedup vs baseline: 1.6112x; 1.6112x over previous
//
#include <hip/hip_runtime.h>
#include <cstdint>
#include <cstddef>

// ---------------------------------------------------------------------------
// PointNet++ (B=8, N=4096, K=64, N1=2048, N2=512, r1=0.2, r2=0.4), fp32.
// Selection stages (FPS argmax, ball-query top-k) are computed with
// __f*_rn intrinsics in numpy's association order so selected index sets
// match the reference bit-exactly; MLP math uses fma freely.
// R9: revert to the R5 configuration — the measured optimum (2501 us).
// R5: FPS is issue+latency bound. Exact lazy pruning: points Morton-bucket-
// sorted in LDS; each thread owns a spatially compact chunk + bbox; a
// conservative box->center lower bound (margin 1e-3, needed ~1e-6) skips the
// whole distance/argmax recompute when it cannot change any mind[j]. min()
// has no rounding -> skipping is bit-exact.
// Key = (d2bits<<24)|((~orig&0xFFF)<<12)|sortedpos: orders by (value, ~orig)
// (numpy argmax tie-break) and carries the winner's sorted position for the
// coord lookup.
// ---------------------------------------------------------------------------

static constexpr int Bc = 8;     // batch (clouds)
static constexpr int Np = 4096;  // points per cloud
static constexpr int Kn = 64;    // max neighbors
static constexpr int M1 = 2048;  // SA1 centers
static constexpr int M2 = 512;   // SA2 centers
static constexpr int LDX = 132;  // row stride of X = [x2 (128) | c2 (3) | pad]

#define DEVINL __device__ __forceinline__

// exact replication of np: ((dx*dx + dy*dy) + dz*dz), no fma contraction
DEVINL float d2_exact(float ax, float ay, float az, float bx, float by, float bz) {
    float dx = __fsub_rn(ax, bx);
    float dy = __fsub_rn(ay, by);
    float dz = __fsub_rn(az, bz);
    float xx = __fmul_rn(dx, dx);
    float yy = __fmul_rn(dy, dy);
    float zz = __fmul_rn(dz, dz);
    return __fadd_rn(__fadd_rn(xx, yy), zz);
}

template <int CTRL, int RM, int BM>
DEVINL unsigned long long dpp_max_step(unsigned long long k) {
    unsigned lo = (unsigned)k, hi = (unsigned)(k >> 32);
    unsigned slo = (unsigned)__builtin_amdgcn_update_dpp(0, (int)lo, CTRL, RM, BM, true);
    unsigned shi = (unsigned)__builtin_amdgcn_update_dpp(0, (int)hi, CTRL, RM, BM, true);
    unsigned long long s = ((unsigned long long)shi << 32) | (unsigned long long)slo;
    return s > k ? s : k;
}

DEVINL unsigned long long wave_max_u64_dpp(unsigned long long k) {
    k = dpp_max_step<0x111, 0xf, 0xf>(k);  // row_shr:1
    k = dpp_max_step<0x112, 0xf, 0xf>(k);  // row_shr:2
    k = dpp_max_step<0x114, 0xf, 0xf>(k);  // row_shr:4
    k = dpp_max_step<0x118, 0xf, 0xf>(k);  // row_shr:8
    k = dpp_max_step<0x142, 0xa, 0xf>(k);  // row_bcast:15
    k = dpp_max_step<0x143, 0xc, 0xf>(k);  // row_bcast:31 -> lane 63 = wave max
    return k;
}

DEVINL unsigned mort3(unsigned v) {  // 3 bits -> bits 0,3,6
    return (v & 1u) | ((v & 2u) << 2) | ((v & 4u) << 4);
}

DEVINL unsigned cell_of(float x, float y, float z) {
    int ix = (int)(x * 8.0f); ix = ix < 0 ? 0 : (ix > 7 ? 7 : ix);
    int iy = (int)(y * 8.0f); iy = iy < 0 ? 0 : (iy > 7 ? 7 : iy);
    int iz = (int)(z * 8.0f); iz = iz < 0 ? 0 : (iz > 7 ? 7 : iz);
    return mort3((unsigned)ix) | (mort3((unsigned)iy) << 1) | (mort3((unsigned)iz) << 2);
}

// inclusive Hillis-Steele scan over 512 entries (thread t owns entry t).
// Returns pointer to the array holding the inclusive scan. 9 barriers.
DEVINL unsigned* scan512(unsigned* h0, unsigned* h1, int t) {
    unsigned* src = h0; unsigned* dst = h1;
    for (int d = 1; d < 512; d <<= 1) {
        unsigned v = src[t];
        if (t >= d) v += src[t - d];
        dst[t] = v;
        __syncthreads();
        unsigned* tmp = src; src = dst; dst = tmp;
    }
    return src;
}

// ---------------------------------------------------------------------------
// Merged FPS with exact pruning: one block (512 thr, 8 waves) per cloud.
// ---------------------------------------------------------------------------
__global__ __launch_bounds__(512)
void fps2x_kernel(const float* __restrict__ pos, float* __restrict__ c1,
                  float* __restrict__ c2, float* __restrict__ X) {
    constexpr int NT = 512;
    __shared__ float scx[Np], scy[Np], scz[Np];  // sorted coords (48 KB)
    __shared__ unsigned spk[Np];                 // ((~orig&0xFFF)<<12)|spos (16 KB)
    __shared__ float s2c[M1 * 3];                // selections, selection order (24 KB)
    __shared__ unsigned h0[512], h1[512];
    __shared__ unsigned long long slots[3];
    const int b = blockIdx.x;
    const int t = threadIdx.x;
    const int lane = t & 63;

    // ===================== phase 1: pos -> c1 =====================
    {
        constexpr int PT = Np / NT;  // 8
        const float* base = pos + (size_t)b * Np * 3;
        float gx[PT], gy[PT], gz[PT];
        unsigned gc[PT];
        #pragma unroll
        for (int j = 0; j < PT; ++j) {
            int p = j * NT + t;
            gx[j] = base[p * 3 + 0];
            gy[j] = base[p * 3 + 1];
            gz[j] = base[p * 3 + 2];
            gc[j] = cell_of(gx[j], gy[j], gz[j]);
        }
        float x0 = base[0], y0 = base[1], z0 = base[2];
        h0[t] = 0;
        if (t == 0) { slots[0] = 0; slots[1] = 0; slots[2] = 0; }
        __syncthreads();
        #pragma unroll
        for (int j = 0; j < PT; ++j) atomicAdd(&h0[gc[j]], 1u);
        __syncthreads();
        unsigned cnt = h0[t];
        unsigned* inc = scan512(h0, h1, t);
        inc[t] -= cnt;                 // exclusive offset -> running cursor
        __syncthreads();
        #pragma unroll
        for (int j = 0; j < PT; ++j) {
            unsigned p = atomicAdd(&inc[gc[j]], 1u);
            scx[p] = gx[j]; scy[p] = gy[j]; scz[p] = gz[j];
            spk[p] = ((0xFFFu - (unsigned)(j * NT + t)) << 12) | p;
        }
        __syncthreads();

        float px[PT], py[PT], pz[PT], mind[PT];
        unsigned oi[PT];
        #pragma unroll
        for (int j = 0; j < PT; ++j) {
            int p = t * PT + j;
            px[j] = scx[p]; py[j] = scy[p]; pz[j] = scz[p];
            oi[j] = spk[p];
        }
        float lox = px[0], hix = px[0], loy = py[0], hiy = py[0], loz = pz[0], hiz = pz[0];
        #pragma unroll
        for (int j = 1; j < PT; ++j) {
            lox = fminf(lox, px[j]); hix = fmaxf(hix, px[j]);
            loy = fminf(loy, py[j]); hiy = fmaxf(hiy, py[j]);
            loz = fminf(loz, pz[j]); hiz = fmaxf(hiz, pz[j]);
        }

        unsigned long long ck = 0;
        #pragma unroll
        for (int j = 0; j < PT; ++j) {
            float d = d2_exact(px[j], py[j], pz[j], x0, y0, z0);
            mind[j] = d;
            unsigned long long kj =
                ((unsigned long long)__float_as_uint(d) << 24) | (unsigned long long)oi[j];
            if (kj > ck) ck = kj;
        }
        float bmax = __uint_as_float((unsigned)(ck >> 24));
        unsigned long long wkey = wave_max_u64_dpp(ck);
        if (lane == 63) atomicMax(&slots[1], wkey);
        if (t == 0) {
            c1[((size_t)b * M1) * 3 + 0] = x0;
            c1[((size_t)b * M1) * 3 + 1] = y0;
            c1[((size_t)b * M1) * 3 + 2] = z0;
            s2c[0] = x0; s2c[1] = y0; s2c[2] = z0;
        }
        int rd = 1, wr = 2, rs = 0;
        for (int s = 1; s < M1; ++s) {
            __syncthreads();
            unsigned long long km = slots[rd];
            if (t == 0) slots[rs] = 0;
            unsigned spos = (unsigned)km & 0xFFFu;
            float cx = scx[spos], cy = scy[spos], cz = scz[spos];
            if (t == 0) {
                c1[((size_t)b * M1 + s) * 3 + 0] = cx;
                c1[((size_t)b * M1 + s) * 3 + 1] = cy;
                c1[((size_t)b * M1 + s) * 3 + 2] = cz;
                s2c[s * 3 + 0] = cx; s2c[s * 3 + 1] = cy; s2c[s * 3 + 2] = cz;
            }
            float dxv = fmaxf(fmaxf(lox - cx, cx - hix), 0.0f);
            float dyv = fmaxf(fmaxf(loy - cy, cy - hiy), 0.0f);
            float dzv = fmaxf(fmaxf(loz - cz, cz - hiz), 0.0f);
            float L = dxv * dxv + dyv * dyv + dzv * dzv;
            bool fire = (L * 0.999f <= bmax);
            if (fire) {
                unsigned long long nck = 0;
                #pragma unroll
                for (int j = 0; j < PT; ++j) {
                    float d = d2_exact(px[j], py[j], pz[j], cx, cy, cz);
                    float m = fminf(mind[j], d);
                    mind[j] = m;
                    unsigned long long kj =
                        ((unsigned long long)__float_as_uint(m) << 24) | (unsigned long long)oi[j];
                    if (kj > nck) nck = kj;
                }
                ck = nck;
                bmax = __uint_as_float((unsigned)(ck >> 24));
            }
            if (__ballot(fire) != 0ull) wkey = wave_max_u64_dpp(ck);
            if (lane == 63) atomicMax(&slots[wr], wkey);
            int nrd = wr; wr = rs; rs = rd; rd = nrd;
        }
    }
    __syncthreads();   // phase-1 done; s2c complete

    // ===================== phase 2: s2c -> c2, X[:,128..130] =====================
    {
        constexpr int PT = M1 / NT;  // 4
        float gx[PT], gy[PT], gz[PT];
        unsigned gc[PT];
        #pragma unroll
        for (int j = 0; j < PT; ++j) {
            int p = j * NT + t;
            gx[j] = s2c[p * 3 + 0];
            gy[j] = s2c[p * 3 + 1];
            gz[j] = s2c[p * 3 + 2];
            gc[j] = cell_of(gx[j], gy[j], gz[j]);
        }
        float x0 = s2c[0], y0 = s2c[1], z0 = s2c[2];
        h0[t] = 0;
        if (t == 0) { slots[0] = 0; slots[1] = 0; slots[2] = 0; }
        __syncthreads();
        #pragma unroll
        for (int j = 0; j < PT; ++j) atomicAdd(&h0[gc[j]], 1u);
        __syncthreads();
        unsigned cnt = h0[t];
        unsigned* inc = scan512(h0, h1, t);
        inc[t] -= cnt;
        __syncthreads();
        #pragma unroll
        for (int j = 0; j < PT; ++j) {
            unsigned p = atomicAdd(&inc[gc[j]], 1u);
            scx[p] = gx[j]; scy[p] = gy[j]; scz[p] = gz[j];
            spk[p] = ((0xFFFu - (unsigned)(j * NT + t)) << 12) | p;
        }
        __syncthreads();

        float px[PT], py[PT], pz[PT], mind[PT];
        unsigned oi[PT];
        #pragma unroll
        for (int j = 0; j < PT; ++j) {
            int p = t * PT + j;
            px[j] = scx[p]; py[j] = scy[p]; pz[j] = scz[p];
            oi[j] = spk[p];
        }
        float lox = px[0], hix = px[0], loy = py[0], hiy = py[0], loz = pz[0], hiz = pz[0];
        #pragma unroll
        for (int j = 1; j < PT; ++j) {
            lox = fminf(lox, px[j]); hix = fmaxf(hix, px[j]);
            loy = fminf(loy, py[j]); hiy = fmaxf(hiy, py[j]);
            loz = fminf(loz, pz[j]); hiz = fmaxf(hiz, pz[j]);
        }

        unsigned long long ck = 0;
        #pragma unroll
        for (int j = 0; j < PT; ++j) {
            float d = d2_exact(px[j], py[j], pz[j], x0, y0, z0);
            mind[j] = d;
            unsigned long long kj =
                ((unsigned long long)__float_as_uint(d) << 24) | (unsigned long long)oi[j];
            if (kj > ck) ck = kj;
        }
        float bmax = __uint_as_float((unsigned)(ck >> 24));
        unsigned long long wkey = wave_max_u64_dpp(ck);
        if (lane == 63) atomicMax(&slots[1], wkey);
        if (t == 0) {
            c2[((size_t)b * M2) * 3 + 0] = x0;
            c2[((size_t)b * M2) * 3 + 1] = y0;
            c2[((size_t)b * M2) * 3 + 2] = z0;
            float* xr = X + (size_t)(b * M2) * LDX;
            xr[128] = x0; xr[129] = y0; xr[130] = z0;
        }
        int rd = 1, wr = 2, rs = 0;
        for (int s = 1; s < M2; ++s) {
            __syncthreads();
            unsigned long long km = slots[rd];
            if (t == 0) slots[rs] = 0;
            unsigned spos = (unsigned)km & 0xFFFu;
            float cx = scx[spos], cy = scy[spos], cz = scz[spos];
            if (t == 0) {
                c2[((size_t)b * M2 + s) * 3 + 0] = cx;
                c2[((size_t)b * M2 + s) * 3 + 1] = cy;
                c2[((size_t)b * M2 + s) * 3 + 2] = cz;
                float* xr = X + (size_t)(b * M2 + s) * LDX;
                xr[128] = cx; xr[129] = cy; xr[130] = cz;
            }
            float dxv = fmaxf(fmaxf(lox - cx, cx - hix), 0.0f);
            float dyv = fmaxf(fmaxf(loy - cy, cy - hiy), 0.0f);
            float dzv = fmaxf(fmaxf(loz - cz, cz - hiz), 0.0f);
            float L = dxv * dxv + dyv * dyv + dzv * dzv;
            bool fire = (L * 0.999f <= bmax);
            if (fire) {
                unsigned long long nck = 0;
                #pragma unroll
                for (int j = 0; j < PT; ++j) {
                    float d = d2_exact(px[j], py[j], pz[j], cx, cy, cz);
                    float m = fminf(mind[j], d);
                    mind[j] = m;
                    unsigned long long kj =
                        ((unsigned long long)__float_as_uint(m) << 24) | (unsigned long long)oi[j];
                    if (kj > nck) nck = kj;
                }
                ck = nck;
                bmax = __uint_as_float((unsigned)(ck >> 24));
            }
            if (__ballot(fire) != 0ull) wkey = wave_max_u64_dpp(ck);
            if (lane == 63) atomicMax(&slots[wr], wkey);
            int nrd = wr; wr = rs; rs = rd; rd = nrd;
        }
    }
}

// ---------------------------------------------------------------------------
// Ball query: one wave per center. d2 per lane in registers; wave-wide counts
// via ballot+popc. If >K in radius: compact candidates (bits,idx) into LDS,
// then exact kth-smallest binary search over the compacted set (~3 chunks
// instead of 64). Ties broken by smallest index (== lax.top_k semantics,
// order within output irrelevant downstream). -1 marks invalid slots.
// ---------------------------------------------------------------------------
template <int NPT>
__global__ __launch_bounds__(256)
void bq_kernel(const float* __restrict__ pts, const float* __restrict__ ctr,
               int mshift, float r2, int* __restrict__ nbr) {
    constexpr int CH = NPT / 64;
    constexpr int CAP = 1024;            // per-wave candidate cap (fallback if exceeded)
    __shared__ uint2 cbuf[4][CAP];
    const int lane = threadIdx.x & 63;
    const int wl = threadIdx.x >> 6;
    int w = __builtin_amdgcn_readfirstlane((int)(blockIdx.x * 4 + wl));
    const int b = w >> mshift;
    const float* pb = pts + (size_t)b * NPT * 3;
    const float* cp = ctr + (size_t)w * 3;
    float cx = cp[0], cy = cp[1], cz = cp[2];
    const unsigned r2b = __float_as_uint(r2);

    unsigned ub[CH];
    int cnt = 0;
    #pragma unroll
    for (int j = 0; j < CH; ++j) {
        int p = j * 64 + lane;
        float d = d2_exact(pb[p * 3 + 0], pb[p * 3 + 1], pb[p * 3 + 2], cx, cy, cz);
        ub[j] = __float_as_uint(d);   // d >= 0 -> bits monotonic
        cnt += __popcll(__ballot(ub[j] <= r2b));
    }
    int* out = nbr + (size_t)w * Kn;
    const unsigned long long lml = (1ull << lane) - 1ull;

    if (cnt <= Kn) {
        int basep = 0;
        #pragma unroll
        for (int j = 0; j < CH; ++j) {
            bool v = ub[j] <= r2b;
            unsigned long long mk = __ballot(v);
            if (v) out[basep + __popcll(mk & lml)] = j * 64 + lane;
            basep += __popcll(mk);
        }
        if (lane >= cnt) out[lane] = -1;
    } else if (cnt <= CAP) {
        // compact candidates (index order preserved: chunk-major, lane-minor)
        uint2* buf = cbuf[wl];
        int basep = 0;
        #pragma unroll
        for (int j = 0; j < CH; ++j) {
            bool v = ub[j] <= r2b;
            unsigned long long mk = __ballot(v);
            if (v) buf[basep + __popcll(mk & lml)] =
                       make_uint2(ub[j], (unsigned)(j * 64 + lane));
            basep += __popcll(mk);
        }
        const int C2 = (cnt + 63) >> 6;   // wave-uniform
        unsigned cb[CAP / 64], ci[CAP / 64];
        #pragma unroll
        for (int e = 0; e < CAP / 64; ++e) {
            if (e >= C2) break;
            int p = e * 64 + lane;
            uint2 v = buf[p];
            cb[e] = (p < cnt) ? v.x : 0xFFFFFFFFu;
            ci[e] = v.y;
        }
        // kth smallest (k=64): smallest t with countLE(t) >= 64
        unsigned lo = 0, hi = r2b;
        while (lo < hi) {
            unsigned mid = lo + ((hi - lo) >> 1);
            int c = 0;
            #pragma unroll
            for (int e = 0; e < CAP / 64; ++e) {
                if (e >= C2) break;
                c += __popcll(__ballot(cb[e] <= mid));
            }
            if (c >= Kn) hi = mid; else lo = mid + 1;
        }
        const unsigned tt = lo;
        int cntLess = 0;
        #pragma unroll
        for (int e = 0; e < CAP / 64; ++e) {
            if (e >= C2) break;
            cntLess += __popcll(__ballot(cb[e] < tt));
        }
        const int quota = Kn - cntLess;
        int baseLt = 0, eqseen = 0;
        #pragma unroll
        for (int e = 0; e < CAP / 64; ++e) {
            if (e >= C2) break;
            bool lt = cb[e] < tt;
            bool eq = cb[e] == tt;
            unsigned long long mlt = __ballot(lt);
            unsigned long long meq = __ballot(eq);
            if (lt) out[baseLt + __popcll(mlt & lml)] = (int)ci[e];
            if (eq) {
                int rr = eqseen + __popcll(meq & lml);
                if (rr < quota) out[cntLess + rr] = (int)ci[e];
            }
            baseLt += __popcll(mlt);
            eqseen += __popcll(meq);
        }
    } else {
        // fallback: exact search over the full per-lane register set
        unsigned lo = 0, hi = r2b;
        while (lo < hi) {
            unsigned mid = lo + ((hi - lo) >> 1);
            int c = 0;
            #pragma unroll
            for (int j = 0; j < CH; ++j) c += __popcll(__ballot(ub[j] <= mid));
            if (c >= Kn) hi = mid; else lo = mid + 1;
        }
        const unsigned tt = lo;
        int cntLess = 0;
        #pragma unroll
        for (int j = 0; j < CH; ++j) cntLess += __popcll(__ballot(ub[j] < tt));
        const int quota = Kn - cntLess;
        int baseLt = 0, eqseen = 0;
        #pragma unroll
        for (int j = 0; j < CH; ++j) {
            bool lt = ub[j] < tt;
            bool eq = ub[j] == tt;
            unsigned long long mlt = __ballot(lt);
            unsigned long long meq = __ballot(eq);
            if (lt) out[baseLt + __popcll(mlt & lml)] = j * 64 + lane;
            if (eq) {
                int rr = eqseen + __popcll(meq & lml);
                if (rr < quota) out[cntLess + rr] = j * 64 + lane;
            }
            baseLt += __popcll(mlt);
            eqseen += __popcll(meq);
        }
    }
}

// ---------------------------------------------------------------------------
// MLP1 (SA1): wave per center, lane per neighbor. 3 -> 64 relu -> 64 relu,
// masked max over neighbors via shfl_xor reduce. Weights pre-transposed:
// w1aT[h] = {w1a[0][h], w1a[1][h], w1a[2][h], b1a[h]}, w1bT[c][h].
// ---------------------------------------------------------------------------
__global__ __launch_bounds__(256)
void mlp1_kernel(const float* __restrict__ pos, const float* __restrict__ c1,
                 const int* __restrict__ nbr, const float* __restrict__ w1aT,
                 const float* __restrict__ w1bT, const float* __restrict__ b1b,
                 float* __restrict__ x1) {
    const int lane = threadIdx.x & 63;
    int w = __builtin_amdgcn_readfirstlane((int)(blockIdx.x * 4 + (threadIdx.x >> 6)));
    const int b = w >> 11;
    const int ii = nbr[(size_t)w * Kn + lane];
    const bool valid = ii >= 0;
    const int i2 = valid ? ii : 0;
    const float* pp = pos + ((size_t)b * Np + i2) * 3;
    const float* cc = c1 + (size_t)w * 3;
    float rx = pp[0] - cc[0], ry = pp[1] - cc[1], rz = pp[2] - cc[2];
    float h1[64];
    #pragma unroll
    for (int h = 0; h < 64; ++h) {
        float4 wv = ((const float4*)w1aT)[h];
        float a = fmaf(rx, wv.x, fmaf(ry, wv.y, fmaf(rz, wv.z, wv.w)));
        h1[h] = fmaxf(a, 0.0f);
    }
    float* orow = x1 + (size_t)w * 64;
    for (int c4 = 0; c4 < 16; ++c4) {
        float v4[4];
        #pragma unroll
        for (int cq = 0; cq < 4; ++cq) {
            int c = c4 * 4 + cq;
            float acc = b1b[c];
            const float4* wr = (const float4*)(w1bT + (size_t)c * 64);
            #pragma unroll
            for (int q = 0; q < 16; ++q) {
                float4 wv = wr[q];
                acc = fmaf(h1[4 * q + 0], wv.x, acc);
                acc = fmaf(h1[4 * q + 1], wv.y, acc);
                acc = fmaf(h1[4 * q + 2], wv.z, acc);
                acc = fmaf(h1[4 * q + 3], wv.w, acc);
            }
            float v = fmaxf(acc, 0.0f);
            v = valid ? v : -__builtin_inff();
            #pragma unroll
            for (int o = 32; o > 0; o >>= 1) v = fmaxf(v, __shfl_xor(v, o, 64));
            v4[cq] = v;
        }
        if (lane == 0)
            ((float4*)orow)[c4] = make_float4(v4[0], v4[1], v4[2], v4[3]);
    }
}

// ---------------------------------------------------------------------------
// MLP2 (SA2): wave per center, lane per neighbor. [x1(64) | relpos(3)] -> 128
// relu -> 128 relu, masked max; writes x2 into X rows (cols 0..127).
// w2aT[h][0..66]=w2a[:,h], [67]=b2a[h], row stride 80. w2bT[c][h].
// ---------------------------------------------------------------------------
__global__ __launch_bounds__(256)
void mlp2_kernel(const float* __restrict__ x1, const float* __restrict__ c1,
                 const float* __restrict__ c2, const int* __restrict__ nbr2,
                 const float* __restrict__ w2aT, const float* __restrict__ w2bT,
                 const float* __restrict__ b2b, float* __restrict__ X) {
    const int lane = threadIdx.x & 63;
    int w = __builtin_amdgcn_readfirstlane((int)(blockIdx.x * 4 + (threadIdx.x >> 6)));
    const int b = w >> 9;
    const int ii = nbr2[(size_t)w * Kn + lane];
    const bool valid = ii >= 0;
    const int i2 = valid ? ii : 0;

    float x[68];
    const float4* xr = (const float4*)(x1 + ((size_t)b * M1 + i2) * 64);
    #pragma unroll
    for (int q = 0; q < 16; ++q) {
        float4 v = xr[q];
        x[4 * q + 0] = v.x; x[4 * q + 1] = v.y;
        x[4 * q + 2] = v.z; x[4 * q + 3] = v.w;
    }
    const float* cc = c2 + (size_t)w * 3;
    const float* cp = c1 + ((size_t)b * M1 + i2) * 3;
    x[64] = cp[0] - cc[0];
    x[65] = cp[1] - cc[1];
    x[66] = cp[2] - cc[2];
    x[67] = 0.0f;

    float h1[128];
    #pragma unroll
    for (int h = 0; h < 128; ++h) {
        const float4* r4 = (const float4*)(w2aT + (size_t)h * 80);
        float acc = 0.0f;
        #pragma unroll
        for (int q = 0; q < 16; ++q) {
            float4 wv = r4[q];
            acc = fmaf(x[4 * q + 0], wv.x, acc);
            acc = fmaf(x[4 * q + 1], wv.y, acc);
            acc = fmaf(x[4 * q + 2], wv.z, acc);
            acc = fmaf(x[4 * q + 3], wv.w, acc);
        }
        float4 tl = r4[16];   // w64, w65, w66, bias
        acc = fmaf(x[64], tl.x, acc);
        acc = fmaf(x[65], tl.y, acc);
        acc = fmaf(x[66], tl.z, acc);
        acc += tl.w;
        h1[h] = fmaxf(acc, 0.0f);
    }
    float* orow = X + (size_t)w * LDX;
    for (int c4 = 0; c4 < 32; ++c4) {
        float v4[4];
        #pragma unroll
        for (int cq = 0; cq < 4; ++cq) {
            int c = c4 * 4 + cq;
            float acc = b2b[c];
            const float4* wr = (const float4*)(w2bT + (size_t)c * 128);
            #pragma unroll
            for (int q = 0; q < 32; ++q) {
                float4 wv = wr[q];
                acc = fmaf(h1[4 * q + 0], wv.x, acc);
                acc = fmaf(h1[4 * q + 1], wv.y, acc);
                acc = fmaf(h1[4 * q + 2], wv.z, acc);
                acc = fmaf(h1[4 * q + 3], wv.w, acc);
            }
            float v = fmaxf(acc, 0.0f);
            v = valid ? v : -__builtin_inff();
            #pragma unroll
            for (int o = 32; o > 0; o >>= 1) v = fmaxf(v, __shfl_xor(v, o, 64));
            v4[cq] = v;
        }
        if (lane == 0) {
            orow[c4 * 4 + 0] = v4[0]; orow[c4 * 4 + 1] = v4[1];
            orow[c4 * 4 + 2] = v4[2]; orow[c4 * 4 + 3] = v4[3];
        }
    }
}

// ---------------------------------------------------------------------------
// GEMM1: H[r][c] = relu(b3a[c] + sum_i X[r][i] * w3a[i][c]), K=131.
// Block per row (uniform X row -> scalar loads), thread per channel.
// ---------------------------------------------------------------------------
__global__ __launch_bounds__(256)
void gemm1_kernel(const float* __restrict__ X, const float* __restrict__ w3a,
                  const float* __restrict__ b3a, float* __restrict__ H) {
    const int r = blockIdx.x;
    const int c = threadIdx.x;
    const float* xr = X + (size_t)r * LDX;
    float acc = b3a[c];
    for (int i = 0; i < 131; ++i)
        acc = fmaf(xr[i], w3a[(size_t)i * 256 + c], acc);
    H[(size_t)r * 256 + c] = fmaxf(acc, 0.0f);
}

// ---------------------------------------------------------------------------
// GEMM2 fused with per-tile row max: 32x64 tile, BK=32, thread = 4 rows x 2
// cols. Epilogue maxes over the 32 rows (all within one cloud) -> partial.
// Bias is added later (uniform per column, commutes with max).
// ---------------------------------------------------------------------------
__global__ __launch_bounds__(256)
void gemm2_kernel(const float* __restrict__ H, const float* __restrict__ w3b,
                  float* __restrict__ part) {
    __shared__ float As[32][33];
    __shared__ float Bs[32][64];
    __shared__ float red[8][64];
    const int bidx = blockIdx.x;
    const int nt = bidx & 15;
    const int mt = (bidx >> 4) & 15;
    const int b = bidx >> 8;
    const int row0 = b * M2 + mt * 32;
    const int col0 = nt * 64;
    const int t = threadIdx.x;
    const int rg = t >> 5, cg = t & 31;

    float acc[4][2] = {{0.f, 0.f}, {0.f, 0.f}, {0.f, 0.f}, {0.f, 0.f}};
    for (int k0 = 0; k0 < 256; k0 += 32) {
        #pragma unroll
        for (int q = 0; q < 4; ++q) {
            int id = t + q * 256;
            As[id >> 5][id & 31] = H[(size_t)(row0 + (id >> 5)) * 256 + k0 + (id & 31)];
        }
        #pragma unroll
        for (int q = 0; q < 8; ++q) {
            int id = t + q * 256;
            Bs[id >> 6][id & 63] = w3b[(size_t)(k0 + (id >> 6)) * 1024 + col0 + (id & 63)];
        }
        __syncthreads();
        #pragma unroll
        for (int kk = 0; kk < 32; ++kk) {
            float b0 = Bs[kk][cg * 2 + 0];
            float b1 = Bs[kk][cg * 2 + 1];
            #pragma unroll
            for (int j = 0; j < 4; ++j) {
                float a = As[rg * 4 + j][kk];
                acc[j][0] = fmaf(a, b0, acc[j][0]);
                acc[j][1] = fmaf(a, b1, acc[j][1]);
            }
        }
        __syncthreads();
    }
    float m0 = fmaxf(fmaxf(acc[0][0], acc[1][0]), fmaxf(acc[2][0], acc[3][0]));
    float m1 = fmaxf(fmaxf(acc[0][1], acc[1][1]), fmaxf(acc[2][1], acc[3][1]));
    red[rg][cg * 2 + 0] = m0;
    red[rg][cg * 2 + 1] = m1;
    __syncthreads();
    if (t < 64) {
        float v = red[0][t];
        #pragma unroll
        for (int q = 1; q < 8; ++q) v = fmaxf(v, red[q][t]);
        part[((size_t)b * 16 + mt) * 1024 + col0 + t] = v;
    }
}

// ---------------------------------------------------------------------------
// Final max over the 16 m-tiles per cloud + bias (no relu on last layer).
// ---------------------------------------------------------------------------
__global__ __launch_bounds__(256)
void rmax_kernel(const float* __restrict__ part, const float* __restrict__ b3b,
                 float* __restrict__ out) {
    int i = blockIdx.x * 256 + threadIdx.x;  // 8192 = B*1024
    int b = i >> 10, c = i & 1023;
    float v = -__builtin_inff();
    #pragma unroll
    for (int tt = 0; tt < 16; ++tt)
        v = fmaxf(v, part[((size_t)b * 16 + tt) * 1024 + c]);
    out[i] = v + b3b[c];
}

// ---------------------------------------------------------------------------
// Weight transposes (recomputed every call; inputs are restored each run).
// ---------------------------------------------------------------------------
__global__ __launch_bounds__(256)
void prep_kernel(const float* __restrict__ w1a, const float* __restrict__ b1a,
                 const float* __restrict__ w1b, const float* __restrict__ w2a,
                 const float* __restrict__ b2a, const float* __restrict__ w2b,
                 float* __restrict__ w1aT, float* __restrict__ w1bT,
                 float* __restrict__ w2aT, float* __restrict__ w2bT) {
    int i = blockIdx.x * 256 + threadIdx.x;  // 0..16383
    if (i < 64 * 4) {
        int h = i >> 2, d = i & 3;
        w1aT[i] = (d < 3) ? w1a[d * 64 + h] : b1a[h];
    }
    if (i < 64 * 64) {
        int c = i >> 6, h = i & 63;
        w1bT[i] = w1b[h * 64 + c];
    }
    if (i < 128 * 80) {
        int h = i / 80, d = i - h * 80;
        w2aT[i] = (d < 67) ? w2a[d * 128 + h] : ((d == 67) ? b2a[h] : 0.0f);
    }
    {
        int c = i >> 7, h = i & 127;
        w2bT[i] = w2b[h * 128 + c];
    }
}

// ---------------------------------------------------------------------------
extern "C" void kernel_launch(void* const* d_in, const int* in_sizes, int n_in,
                              void* d_out, int out_size, void* d_ws, size_t ws_size,
                              hipStream_t stream) {
    const float* pos = (const float*)d_in[0];
    const float* w1a = (const float*)d_in[1];
    const float* b1a = (const float*)d_in[2];
    const float* w1b = (const float*)d_in[3];
    const float* b1b = (const float*)d_in[4];
    const float* w2a = (const float*)d_in[5];
    const float* b2a = (const float*)d_in[6];
    const float* w2b = (const float*)d_in[7];
    const float* b2b = (const float*)d_in[8];
    const float* w3a = (const float*)d_in[9];
    const float* b3a = (const float*)d_in[10];
    const float* w3b = (const float*)d_in[11];
    const float* b3b = (const float*)d_in[12];
    float* out = (float*)d_out;

    char* ws = (char*)d_ws;
    size_t off = 0;
    auto alloc = [&](size_t bytes) -> char* {
        char* p = ws + off;
        off += (bytes + 255) & ~(size_t)255;
        return p;
    };
    float* c1   = (float*)alloc(sizeof(float) * Bc * M1 * 3);
    float* c2   = (float*)alloc(sizeof(float) * Bc * M2 * 3);
    int*   nbr1 = (int*)alloc(sizeof(int) * Bc * M1 * Kn);
    int*   nbr2 = (int*)alloc(sizeof(int) * Bc * M2 * Kn);
    float* x1   = (float*)alloc(sizeof(float) * Bc * M1 * 64);
    float* X    = (float*)alloc(sizeof(float) * Bc * M2 * LDX);
    float* H    = (float*)alloc(sizeof(float) * Bc * M2 * 256);
    float* part = (float*)alloc(sizeof(float) * Bc * 16 * 1024);
    float* w1aT = (float*)alloc(sizeof(float) * 64 * 4);
    float* w1bT = (float*)alloc(sizeof(float) * 64 * 64);
    float* w2aT = (float*)alloc(sizeof(float) * 128 * 80);
    float* w2bT = (float*)alloc(sizeof(float) * 128 * 128);

    prep_kernel<<<dim3(64), dim3(256), 0, stream>>>(w1a, b1a, w1b, w2a, b2a, w2b,
                                                    w1aT, w1bT, w2aT, w2bT);
    fps2x_kernel<<<dim3(Bc), dim3(512), 0, stream>>>(pos, c1, c2, X);
    bq_kernel<Np><<<dim3(Bc * M1 / 4), dim3(256), 0, stream>>>(
        pos, c1, 11, (float)(0.2 * 0.2), nbr1);
    mlp1_kernel<<<dim3(Bc * M1 / 4), dim3(256), 0, stream>>>(
        pos, c1, nbr1, w1aT, w1bT, b1b, x1);
    bq_kernel<M1><<<dim3(Bc * M2 / 4), dim3(256), 0, stream>>>(
        c1, c2, 9, (float)(0.4 * 0.4), nbr2);
    mlp2_kernel<<<dim3(Bc * M2 / 4), dim3(256), 0, stream>>>(
        x1, c1, c2, nbr2, w2aT, w2bT, b2b, X);
    gemm1_kernel<<<dim3(Bc * M2), dim3(256), 0, stream>>>(X, w3a, b3a, H);
    gemm2_kernel<<<dim3(Bc * 16 * 16), dim3(256), 0, stream>>>(H, w3b, part);
    rmax_kernel<<<dim3(32), dim3(256), 0, stream>>>(part, b3b, out);
}